// Round 4
// baseline (97.652 us; speedup 1.0000x reference)
//
#include <hip/hip_runtime.h>

#define NROWS 32768
#define NE    1024
#define ED    64

typedef float4 f4;

// ---------------------------------------------------------------------------
// Prep: per-code ||e||^2 with numpy pairwise-8 op order (exact f32 replication)
// ---------------------------------------------------------------------------
__global__ void vq_prep(const float* __restrict__ cb, float* __restrict__ ssq)
{
    int j = blockIdx.x * blockDim.x + threadIdx.x;   // 0..1023
    const f4* crow = (const f4*)(cb + (size_t)j * ED);
    float v[ED];
#pragma unroll
    for (int i = 0; i < 16; ++i) {
        f4 t = crow[i];
        v[4*i+0] = t.x; v[4*i+1] = t.y; v[4*i+2] = t.z; v[4*i+3] = t.w;
    }
    {
#pragma clang fp contract(off)
        float r0 = v[0]*v[0], r1 = v[1]*v[1], r2 = v[2]*v[2], r3 = v[3]*v[3];
        float r4 = v[4]*v[4], r5 = v[5]*v[5], r6 = v[6]*v[6], r7 = v[7]*v[7];
#pragma unroll
        for (int i = 8; i < ED; i += 8) {
            r0 += v[i+0]*v[i+0]; r1 += v[i+1]*v[i+1];
            r2 += v[i+2]*v[i+2]; r3 += v[i+3]*v[i+3];
            r4 += v[i+4]*v[i+4]; r5 += v[i+5]*v[i+5];
            r6 += v[i+6]*v[i+6]; r7 += v[i+7]*v[i+7];
        }
        ssq[j] = ((r0+r1)+(r2+r3)) + ((r4+r5)+(r6+r7));
    }
}

// ---------------------------------------------------------------------------
// Main: lane = row (64 rows/block in VGPRs), 8 waves split the 1024 codes
// into ranges of 128. Codebook read via wave-uniform scalar loads (SGPR
// operand to v_fmac) -> inner loop is pure FMA, no LDS, no per-lane VMEM.
// Numerics identical to the passing round-3 kernel:
//   cn, ssq: numpy pairwise-8; dot: ascending-k single-acc fmaf;
//   d = fl(fl(cn+ssq_j) - 2*dot); argmin ascending j, strict < (first index).
// ---------------------------------------------------------------------------
__global__ __launch_bounds__(512, 4)
void vq_main(const float* __restrict__ z, const float* __restrict__ cb,
             const float* __restrict__ ssq, float* __restrict__ out,
             float* __restrict__ partials)
{
    __shared__ float cv[8][64];
    __shared__ int   ci[8][64];
    __shared__ int   idxsh[64];
    __shared__ float wsum[8];

    const int tid  = threadIdx.x;
    const int lane = tid & 63;
    const int w    = tid >> 6;              // wave 0..7
    const int rowbase = blockIdx.x * 64;
    const int grow    = rowbase + lane;     // this lane's z-row

    // ---- own row -> registers (16 x float4) ----
    float zr[ED];
    {
        const f4* zrow = (const f4*)(z + (size_t)grow * ED);
#pragma unroll
        for (int i = 0; i < 16; ++i) {
            f4 t = zrow[i];
            zr[4*i+0] = t.x; zr[4*i+1] = t.y; zr[4*i+2] = t.z; zr[4*i+3] = t.w;
        }
    }

    // ---- row norm, numpy pairwise-8 ----
    float cn;
    {
#pragma clang fp contract(off)
        float r0 = zr[0]*zr[0], r1 = zr[1]*zr[1], r2 = zr[2]*zr[2], r3 = zr[3]*zr[3];
        float r4 = zr[4]*zr[4], r5 = zr[5]*zr[5], r6 = zr[6]*zr[6], r7 = zr[7]*zr[7];
#pragma unroll
        for (int i = 8; i < ED; i += 8) {
            r0 += zr[i+0]*zr[i+0]; r1 += zr[i+1]*zr[i+1];
            r2 += zr[i+2]*zr[i+2]; r3 += zr[i+3]*zr[i+3];
            r4 += zr[i+4]*zr[i+4]; r5 += zr[i+5]*zr[i+5];
            r6 += zr[i+6]*zr[i+6]; r7 += zr[i+7]*zr[i+7];
        }
        cn = ((r0+r1)+(r2+r3)) + ((r4+r5)+(r6+r7));
    }

    // ---- scan this wave's 128-code range; codebook via scalar loads ----
    float bv = INFINITY;
    int   bi = 0;
    const int jbase = __builtin_amdgcn_readfirstlane(w * 128);  // provably uniform

    for (int jj = 0; jj < 128; jj += 2) {
        const int j0 = jbase + jj;
        const float* c0 = cb + (size_t)j0 * ED;   // uniform pointer -> s_load
        float a0 = 0.f, a1 = 0.f;
#pragma unroll
        for (int k = 0; k < ED; ++k) {
            a0 = fmaf(c0[k],      zr[k], a0);     // two independent fma chains
            a1 = fmaf(c0[ED + k], zr[k], a1);
        }
        {
#pragma clang fp contract(off)
            float t0 = cn + ssq[j0];
            float t1 = cn + ssq[j0 + 1];
            float d0 = t0 - 2.0f * a0;            // 2*a exact
            float d1 = t1 - 2.0f * a1;
            if (d0 < bv) { bv = d0; bi = j0; }
            if (d1 < bv) { bv = d1; bi = j0 + 1; }
        }
    }

    cv[w][lane] = bv;
    ci[w][lane] = bi;
    __syncthreads();

    // ---- combine 8 wave-candidates per row (ascending range, strict <) ----
    if (tid < 64) {
        float v = cv[0][tid]; int i = ci[0][tid];
#pragma unroll
        for (int u = 1; u < 8; ++u) {
            float vu = cv[u][tid]; int iu = ci[u][tid];
            if (vu < v) { v = vu; i = iu; }
        }
        i &= (NE - 1);                       // defensive no-op
        idxsh[tid] = i;
        out[(size_t)NROWS * ED + rowbase + tid] = (float)i;   // idx as f32
    }
    __syncthreads();

    // ---- epilogue: thread -> row=lane, dims [w*8, w*8+8) ----
    const int i = idxsh[lane];
    const f4* eq  = (const f4*)(cb + (size_t)i * ED + w * 8);
    const f4* zg2 = (const f4*)(z  + (size_t)grow * ED + w * 8);
    f4 e0 = eq[0],  e1 = eq[1];
    f4 z0 = zg2[0], z1 = zg2[1];
    float lp = 0.f;
    f4 o0, o1;
    {
#pragma clang fp contract(off)
        float d;
        d = e0.x - z0.x; o0.x = z0.x + d; lp += d*d;
        d = e0.y - z0.y; o0.y = z0.y + d; lp += d*d;
        d = e0.z - z0.z; o0.z = z0.z + d; lp += d*d;
        d = e0.w - z0.w; o0.w = z0.w + d; lp += d*d;
        d = e1.x - z1.x; o1.x = z1.x + d; lp += d*d;
        d = e1.y - z1.y; o1.y = z1.y + d; lp += d*d;
        d = e1.z - z1.z; o1.z = z1.z + d; lp += d*d;
        d = e1.w - z1.w; o1.w = z1.w + d; lp += d*d;
    }
    f4* og = (f4*)(out + (size_t)grow * ED + w * 8);
    og[0] = o0; og[1] = o1;

    // ---- deterministic loss partial ----
#pragma unroll
    for (int m = 1; m < 64; m <<= 1) lp += __shfl_xor(lp, m);
    if (lane == 0) wsum[w] = lp;
    __syncthreads();
    if (tid == 0)
        partials[blockIdx.x] = (((wsum[0]+wsum[1]) + (wsum[2]+wsum[3]))
                              + ((wsum[4]+wsum[5]) + (wsum[6]+wsum[7])));
}

// ---------------------------------------------------------------------------
// Finalize: deterministic tree-sum of 512 partials -> loss scalar (f32)
// ---------------------------------------------------------------------------
__global__ void vq_finalize(const float* __restrict__ partials,
                            float* __restrict__ out)
{
    __shared__ float red[256];
    int t = threadIdx.x;
    red[t] = partials[t] + partials[t + 256];
    __syncthreads();
    for (int m = 128; m > 0; m >>= 1) {
        if (t < m) red[t] += red[t + m];
        __syncthreads();
    }
    if (t == 0) {
        float mean = red[0] / (float)((size_t)NROWS * ED);
        out[(size_t)NROWS * ED + NROWS] = mean + 0.25f * mean;  // (1+BETA)*mean
    }
}

extern "C" void kernel_launch(void* const* d_in, const int* in_sizes, int n_in,
                              void* d_out, int out_size, void* d_ws, size_t ws_size,
                              hipStream_t stream)
{
    (void)in_sizes; (void)n_in; (void)out_size; (void)ws_size;
    const float* z  = (const float*)d_in[0];
    const float* cb = (const float*)d_in[1];
    float* out = (float*)d_out;
    float* ssq      = (float*)d_ws;          // 1024 f32
    float* partials = ssq + NE;              // 512 f32

    vq_prep<<<4, 256, 0, stream>>>(cb, ssq);
    vq_main<<<512, 512, 0, stream>>>(z, cb, ssq, out, partials);
    vq_finalize<<<1, 256, 0, stream>>>(partials, out);
}